// Round 1
// baseline (1104.763 us; speedup 1.0000x reference)
//
#include <hip/hip_runtime.h>
#include <stdint.h>

#define Mdim 8192
#define Kdim 4096
#define Ndim 11008
#define KBLK 32            // Kdim / 128
#define NBLK 86            // Ndim / 128
#define FP8MAX 448.0f
#define QEPS 1e-12f

typedef float v4f __attribute__((ext_vector_type(4)));

__device__ __forceinline__ void async16(void* lds, const void* g) {
  __builtin_amdgcn_global_load_lds(
      (const __attribute__((address_space(1))) unsigned int*)g,
      (__attribute__((address_space(3))) unsigned int*)lds, 16, 0, 0);
}

// ---------------- activation quantize: (1 x 128) blocks along K ----------------
// 32 lanes per block, 4 elems/lane via float4. Scales stored transposed [KBLK][M].
__global__ __launch_bounds__(256) void quant_x_kernel(const float* __restrict__ x,
                                                      uint8_t* __restrict__ qx,
                                                      float* __restrict__ sx) {
  const int tid = blockIdx.x * 256 + threadIdx.x;
  const int64_t base = (int64_t)tid * 4;
  const float4 v = *(const float4*)(x + base);
  float a = fmaxf(fmaxf(fabsf(v.x), fabsf(v.y)), fmaxf(fabsf(v.z), fabsf(v.w)));
#pragma unroll
  for (int off = 16; off >= 1; off >>= 1) a = fmaxf(a, __shfl_xor(a, off, 32));
  const float scale = fmaxf(a, QEPS) / FP8MAX;  // same rounding chain as reference
  int p = __builtin_amdgcn_cvt_pk_fp8_f32(v.x / scale, v.y / scale, 0, false);
  p = __builtin_amdgcn_cvt_pk_fp8_f32(v.z / scale, v.w / scale, p, true);
  *(int*)(qx + base) = p;
  if ((threadIdx.x & 31) == 0) {
    const int blk = tid >> 5;   // linear 128-block id
    const int m = blk >> 5;     // blk / (K/128)
    const int kb = blk & 31;    // blk % (K/128)
    sx[kb * Mdim + m] = scale;
  }
}

// ---------------- weight quantize: (128 x 128) blocks ----------------
// One 256-thread block per weight block; 64 elems/thread kept in registers.
__global__ __launch_bounds__(256) void quant_w_kernel(const float* __restrict__ w,
                                                      uint8_t* __restrict__ qw,
                                                      float* __restrict__ sw) {
  const int kb = blockIdx.x, nb = blockIdx.y;
  const int t = threadIdx.x;
  const int r = t >> 1;              // row within block: 0..127
  const int c0 = (t & 1) * 64;       // col start: 0 or 64
  const int64_t gbase = (int64_t)(nb * 128 + r) * Kdim + kb * 128 + c0;
  float4 v[16];
  float a = 0.0f;
#pragma unroll
  for (int i = 0; i < 16; ++i) {
    v[i] = *(const float4*)(w + gbase + i * 4);
    a = fmaxf(a, fmaxf(fmaxf(fabsf(v[i].x), fabsf(v[i].y)),
                       fmaxf(fabsf(v[i].z), fabsf(v[i].w))));
  }
#pragma unroll
  for (int off = 32; off >= 1; off >>= 1) a = fmaxf(a, __shfl_xor(a, off, 64));
  __shared__ float red[4];
  if ((t & 63) == 0) red[t >> 6] = a;
  __syncthreads();
  a = fmaxf(fmaxf(red[0], red[1]), fmaxf(red[2], red[3]));
  const float scale = fmaxf(a, QEPS) / FP8MAX;
#pragma unroll
  for (int i = 0; i < 16; ++i) {
    int p = __builtin_amdgcn_cvt_pk_fp8_f32(v[i].x / scale, v[i].y / scale, 0, false);
    p = __builtin_amdgcn_cvt_pk_fp8_f32(v[i].z / scale, v[i].w / scale, p, true);
    *(int*)(qw + gbase + i * 4) = p;
  }
  if (t == 0) sw[nb * KBLK + kb] = scale;
}

// ---------------- blockwise-fp8 GEMM: out = (qx*sx) @ (qw*sw)^T + bias ----------------
// BM=BN=BK=128; 4 waves in 2x2; each wave 4x4 grid of 16x16x32 fp8 MFMAs.
// LDS tiles XOR-swizzled (rule 21: linear gload_lds dest + pre-swizzled global
// source col + swizzled read col). Single live inner v4f per (i,j) to keep
// VGPR <= 170 for 3 waves/SIMD.
__global__ __launch_bounds__(256, 3) void gemm_kernel(
    const uint8_t* __restrict__ qx, const uint8_t* __restrict__ qw,
    const float* __restrict__ sx, const float* __restrict__ sw,
    const float* __restrict__ bias, float* __restrict__ out) {
  __shared__ __align__(16) uint8_t As[128 * 128];
  __shared__ __align__(16) uint8_t Bs[128 * 128];
  __shared__ __align__(16) float Ssx[KBLK][128];   // all act scales for this M-strip
  __shared__ float Ssw[KBLK];                      // all weight scales for this N-block

  const int tid = threadIdx.x;
  const int wid = tid >> 6;
  const int lane = tid & 63;
  const int bn = blockIdx.x, bm = blockIdx.y;
  const int wm = wid >> 1, wn = wid & 1;
  const int m0 = bm * 128, n0 = bn * 128;
  const int lr = lane & 15;   // A row / B row / C col
  const int lq = lane >> 4;   // lane quad
  // swizzled read-col lane constant: (ks*32 + lq*8) ^ ((row&7)<<4), row&7 == lr&7
  const int cbase = (lq * 8) ^ ((lr & 7) << 4);

  const v4f zero4 = {0.f, 0.f, 0.f, 0.f};
  v4f acc[4][4];
#pragma unroll
  for (int i = 0; i < 4; ++i)
#pragma unroll
    for (int j = 0; j < 4; ++j) acc[i][j] = zero4;

  // ---- prologue: stage ALL scales for this block into LDS once ----
#pragma unroll
  for (int rr = 0; rr < 4; ++rr) {
    const int f = tid + rr * 256;        // float4 index, 0..1023
    const int kb = f >> 5;               // 32 float4 per kb row
    const int mrel = (f & 31) * 4;
    *(v4f*)&Ssx[kb][mrel] = *(const v4f*)(sx + (int64_t)kb * Mdim + m0 + mrel);
  }
  if (tid < KBLK) Ssw[tid] = sw[bn * KBLK + tid];
  // visibility guaranteed by the first __syncthreads in the K-loop

  // staging: thread t loads 16B; LDS dest = wave-uniform base + lane*16 (linear).
  // Global source col is pre-swizzled so that LDS[row][c] = G[row][c ^ ((row&7)<<4)].
  const int srow = tid >> 3;
  const int scol = ((tid & 7) << 4) ^ ((srow & 7) << 4);  // (srow+j*32)&7 == srow&7
  const uint8_t* gA = qx + (int64_t)(m0 + srow) * Kdim + scol;
  const uint8_t* gB = qw + (int64_t)(n0 + srow) * Kdim + scol;
  uint8_t* ldsA = As + wid * 1024;
  uint8_t* ldsB = Bs + wid * 1024;

  for (int kb = 0; kb < KBLK; ++kb) {
    const int koff = kb * 128;
#pragma unroll
    for (int j = 0; j < 4; ++j) {
      async16(ldsA + j * 4096, gA + (int64_t)(j * 32) * Kdim + koff);
      async16(ldsB + j * 4096, gB + (int64_t)(j * 32) * Kdim + koff);
    }
    __syncthreads();  // drains vmcnt -> async LDS writes visible

    // all 16 B fragments resident (32 VGPR)
    long long bfr[4][4];
#pragma unroll
    for (int ks = 0; ks < 4; ++ks)
#pragma unroll
      for (int j = 0; j < 4; ++j)
        bfr[ks][j] = *(const long long*)(Bs + (wn * 64 + j * 16 + lr) * 128 +
                                         ((ks * 32) ^ cbase));

    const float sww = Ssw[kb];
#pragma unroll
    for (int i = 0; i < 4; ++i) {
      const int arow = (wm * 64 + i * 16 + lr) * 128;
      const long long a0 = *(const long long*)(As + arow + ((0) ^ cbase));
      const long long a1 = *(const long long*)(As + arow + ((32) ^ cbase));
      const long long a2 = *(const long long*)(As + arow + ((64) ^ cbase));
      const long long a3 = *(const long long*)(As + arow + ((96) ^ cbase));
      v4f s4 = *(const v4f*)&Ssx[kb][wm * 64 + i * 16 + lq * 4];
      s4 *= sww;
#pragma unroll
      for (int j = 0; j < 4; ++j) {
        v4f t = __builtin_amdgcn_mfma_f32_16x16x32_fp8_fp8(a0, bfr[0][j], zero4, 0, 0, 0);
        t = __builtin_amdgcn_mfma_f32_16x16x32_fp8_fp8(a1, bfr[1][j], t, 0, 0, 0);
        t = __builtin_amdgcn_mfma_f32_16x16x32_fp8_fp8(a2, bfr[2][j], t, 0, 0, 0);
        t = __builtin_amdgcn_mfma_f32_16x16x32_fp8_fp8(a3, bfr[3][j], t, 0, 0, 0);
        acc[i][j] += s4 * t;
      }
    }
    __syncthreads();  // protect LDS before next stage
  }

  // epilogue: C layout col=lane&15, row=(lane>>4)*4+reg
#pragma unroll
  for (int i = 0; i < 4; ++i) {
    const int grow = m0 + wm * 64 + i * 16 + lq * 4;
#pragma unroll
    for (int j = 0; j < 4; ++j) {
      const int gcol = n0 + wn * 64 + j * 16 + lr;
      const float bv = bias[gcol];
      float* p = out + (int64_t)grow * Ndim + gcol;
      p[0] = acc[i][j][0] + bv;
      p[Ndim] = acc[i][j][1] + bv;
      p[2 * Ndim] = acc[i][j][2] + bv;
      p[3 * Ndim] = acc[i][j][3] + bv;
    }
  }
}

extern "C" void kernel_launch(void* const* d_in, const int* in_sizes, int n_in,
                              void* d_out, int out_size, void* d_ws, size_t ws_size,
                              hipStream_t stream) {
  const float* x = (const float*)d_in[0];
  const float* w = (const float*)d_in[1];
  const float* bias = (const float*)d_in[2];
  float* out = (float*)d_out;

  uint8_t* ws = (uint8_t*)d_ws;
  uint8_t* qx = ws;                                  // M*K fp8
  uint8_t* qw = qx + (size_t)Mdim * Kdim;            // N*K fp8
  float* sx = (float*)(qw + (size_t)Ndim * Kdim);    // [KBLK][M]
  float* sw = sx + (size_t)KBLK * Mdim;              // [NBLK][KBLK]

  quant_x_kernel<<<(Mdim / 256) * (Kdim / 4), 256, 0, stream>>>(x, qx, sx);
  quant_w_kernel<<<dim3(KBLK, NBLK), 256, 0, stream>>>(w, qw, sw);
  gemm_kernel<<<dim3(NBLK, Mdim / 128), 256, 0, stream>>>(qx, qw, sx, sw, bias, out);
}

// Round 2
// 1013.980 us; speedup vs baseline: 1.0895x; 1.0895x over previous
//
#include <hip/hip_runtime.h>
#include <stdint.h>

#define Mdim 8192
#define Kdim 4096
#define Ndim 11008
#define KBLK 32            // Kdim / 128
#define NBLK 86            // Ndim / 128
#define FP8MAX 448.0f
#define QEPS 1e-12f

typedef float v4f __attribute__((ext_vector_type(4)));
typedef int v4i __attribute__((ext_vector_type(4)));
typedef int v8i __attribute__((ext_vector_type(8)));

__device__ __forceinline__ void async16(void* lds, const void* g) {
  __builtin_amdgcn_global_load_lds(
      (const __attribute__((address_space(1))) unsigned int*)g,
      (__attribute__((address_space(3))) unsigned int*)lds, 16, 0, 0);
}

// ---------------- activation quantize: (1 x 128) blocks along K ----------------
// 16 elems/thread (4x float4); 8 lanes per 128-block; 16B packed stores.
__global__ __launch_bounds__(256) void quant_x_kernel(const float* __restrict__ x,
                                                      uint8_t* __restrict__ qx,
                                                      float* __restrict__ sx) {
  const int tid = blockIdx.x * 256 + threadIdx.x;
  const int64_t base = (int64_t)tid * 16;
  float4 v[4];
  float a = 0.0f;
#pragma unroll
  for (int i = 0; i < 4; ++i) {
    v[i] = *(const float4*)(x + base + i * 4);
    a = fmaxf(a, fmaxf(fmaxf(fabsf(v[i].x), fabsf(v[i].y)),
                       fmaxf(fabsf(v[i].z), fabsf(v[i].w))));
  }
#pragma unroll
  for (int off = 4; off >= 1; off >>= 1) a = fmaxf(a, __shfl_xor(a, off, 8));
  const float scale = fmaxf(a, QEPS) / FP8MAX;  // same rounding chain as reference
  v4i q;
#pragma unroll
  for (int i = 0; i < 4; ++i) {
    int p = __builtin_amdgcn_cvt_pk_fp8_f32(v[i].x / scale, v[i].y / scale, 0, false);
    p = __builtin_amdgcn_cvt_pk_fp8_f32(v[i].z / scale, v[i].w / scale, p, true);
    q[i] = p;
  }
  *(v4i*)(qx + base) = q;
  if ((threadIdx.x & 7) == 0) {
    const int blk = tid >> 3;   // linear 128-block id
    const int m = blk >> 5;     // blk / (K/128)
    const int kb = blk & 31;    // blk % (K/128)
    sx[kb * Mdim + m] = scale;
  }
}

// ---------------- weight quantize: (128 x 128) blocks ----------------
// Coalesced: 32 threads per row (128B contiguous loads/stores), 8 rows/step, 16 steps.
__global__ __launch_bounds__(256) void quant_w_kernel(const float* __restrict__ w,
                                                      uint8_t* __restrict__ qw,
                                                      float* __restrict__ sw) {
  const int kb = blockIdx.x, nb = blockIdx.y;
  const int t = threadIdx.x;
  const int rs = t >> 5;             // row within step: 0..7
  const int cc = (t & 31) * 4;       // float col within block: 0..124
  const float* wb = w + (int64_t)(nb * 128) * Kdim + kb * 128;
  float4 v[16];
  float a = 0.0f;
#pragma unroll
  for (int s = 0; s < 16; ++s) {
    v[s] = *(const float4*)(wb + (int64_t)(s * 8 + rs) * Kdim + cc);
    a = fmaxf(a, fmaxf(fmaxf(fabsf(v[s].x), fabsf(v[s].y)),
                       fmaxf(fabsf(v[s].z), fabsf(v[s].w))));
  }
#pragma unroll
  for (int off = 32; off >= 1; off >>= 1) a = fmaxf(a, __shfl_xor(a, off, 64));
  __shared__ float red[4];
  if ((t & 63) == 0) red[t >> 6] = a;
  __syncthreads();
  a = fmaxf(fmaxf(red[0], red[1]), fmaxf(red[2], red[3]));
  const float scale = fmaxf(a, QEPS) / FP8MAX;
  uint8_t* qb = qw + (int64_t)(nb * 128) * Kdim + kb * 128;
#pragma unroll
  for (int s = 0; s < 16; ++s) {
    int p = __builtin_amdgcn_cvt_pk_fp8_f32(v[s].x / scale, v[s].y / scale, 0, false);
    p = __builtin_amdgcn_cvt_pk_fp8_f32(v[s].z / scale, v[s].w / scale, p, true);
    *(int*)(qb + (int64_t)(s * 8 + rs) * Kdim + cc) = p;
  }
  if (t == 0) sw[nb * KBLK + kb] = scale;
}

// ---------------- blockwise-fp8 GEMM: out = (qx*sx) @ (qw*sw)^T + bias ----------------
// BM=BN=BK=128; 4 waves in 2x2; each wave 4x4 grid of 16x16x128 MX-fp8 MFMAs with
// UNIT hw scales (0x7F = e8m0 1.0) — fp32 block scales applied outside, unchanged.
// LDS XOR-swizzled (linear gload_lds dest + pre-swizzled global source + swizzled read).
__global__ __launch_bounds__(256, 3) void gemm_kernel(
    const uint8_t* __restrict__ qx, const uint8_t* __restrict__ qw,
    const float* __restrict__ sx, const float* __restrict__ sw,
    const float* __restrict__ bias, float* __restrict__ out) {
  __shared__ __align__(16) uint8_t As[128 * 128];
  __shared__ __align__(16) uint8_t Bs[128 * 128];
  __shared__ __align__(16) float Ssx[KBLK][128];   // all act scales for this M-strip
  __shared__ float Ssw[KBLK];                      // all weight scales for this N-block

  const int tid = threadIdx.x;
  const int wid = tid >> 6;
  const int lane = tid & 63;
  const int bn = blockIdx.x, bm = blockIdx.y;
  const int wm = wid >> 1, wn = wid & 1;
  const int m0 = bm * 128, n0 = bn * 128;
  const int lr = lane & 15;   // A row / B row / C col
  const int lq = lane >> 4;   // lane quad -> K chunk of 32
  const int cswz = (lr & 7) << 4;           // read-side XOR (row&7 == lr&7)
  const int c0 = (lq * 32) ^ cswz;          // swizzled col of K-bytes 0..15
  const int c1 = (lq * 32 + 16) ^ cswz;     // swizzled col of K-bytes 16..31

  const v4f zero4 = {0.f, 0.f, 0.f, 0.f};
  v4f acc[4][4];
#pragma unroll
  for (int i = 0; i < 4; ++i)
#pragma unroll
    for (int j = 0; j < 4; ++j) acc[i][j] = zero4;

  // ---- prologue: stage ALL scales for this block into LDS once ----
#pragma unroll
  for (int rr = 0; rr < 4; ++rr) {
    const int f = tid + rr * 256;        // float4 index, 0..1023
    const int kb = f >> 5;               // 32 float4 per kb row
    const int mrel = (f & 31) * 4;
    *(v4f*)&Ssx[kb][mrel] = *(const v4f*)(sx + (int64_t)kb * Mdim + m0 + mrel);
  }
  if (tid < KBLK) Ssw[tid] = sw[bn * KBLK + tid];
  // visibility guaranteed by the first __syncthreads in the K-loop

  // staging: thread t loads 16B; LDS dest = linear (tid*16 + j*4096).
  // Global source col pre-swizzled so LDS[row][c] = G[row][c ^ ((row&7)<<4)].
  const int srow = tid >> 3;
  const int scol = ((tid & 7) << 4) ^ ((srow & 7) << 4);  // (srow+j*32)&7 == srow&7
  const uint8_t* gA = qx + (int64_t)(m0 + srow) * Kdim + scol;
  const uint8_t* gB = qw + (int64_t)(n0 + srow) * Kdim + scol;
  uint8_t* ldsA = As + wid * 1024;
  uint8_t* ldsB = Bs + wid * 1024;

  for (int kb = 0; kb < KBLK; ++kb) {
    const int koff = kb * 128;
#pragma unroll
    for (int j = 0; j < 4; ++j) {
      async16(ldsA + j * 4096, gA + (int64_t)(j * 32) * Kdim + koff);
      async16(ldsB + j * 4096, gB + (int64_t)(j * 32) * Kdim + koff);
    }
    __syncthreads();  // drains vmcnt -> async LDS writes visible

    // all 4 B fragments resident (32 VGPR): per lane 32 K-bytes as 2x b128
    v8i bfr[4];
#pragma unroll
    for (int j = 0; j < 4; ++j) {
      const uint8_t* bp = Bs + (wn * 64 + j * 16 + lr) * 128;
      v4i lo = *(const v4i*)(bp + c0);
      v4i hi = *(const v4i*)(bp + c1);
      bfr[j] = __builtin_shufflevector(lo, hi, 0, 1, 2, 3, 4, 5, 6, 7);
    }

    const float sww = Ssw[kb];
#pragma unroll
    for (int i = 0; i < 4; ++i) {
      const uint8_t* ap = As + (wm * 64 + i * 16 + lr) * 128;
      v4i lo = *(const v4i*)(ap + c0);
      v4i hi = *(const v4i*)(ap + c1);
      v8i af = __builtin_shufflevector(lo, hi, 0, 1, 2, 3, 4, 5, 6, 7);
      v4f s4 = *(const v4f*)&Ssx[kb][wm * 64 + i * 16 + lq * 4];
      s4 *= sww;
#pragma unroll
      for (int j = 0; j < 4; ++j) {
        // fp8(e4m3) A/B, unit e8m0 scales (0x7F per 32-block) => exact
        v4f t = __builtin_amdgcn_mfma_scale_f32_16x16x128_f8f6f4(
            af, bfr[j], zero4, 0, 0, 0, 0x7F7F7F7F, 0, 0x7F7F7F7F);
        acc[i][j] += s4 * t;
      }
    }
    __syncthreads();  // protect LDS before next stage
  }

  // epilogue: C layout col=lane&15, row=(lane>>4)*4+reg
#pragma unroll
  for (int j = 0; j < 4; ++j) {
    const int gcol = n0 + wn * 64 + j * 16 + lr;
    const float bv = bias[gcol];
#pragma unroll
    for (int i = 0; i < 4; ++i) {
      const int grow = m0 + wm * 64 + i * 16 + lq * 4;
      float* p = out + (int64_t)grow * Ndim + gcol;
      p[0] = acc[i][j][0] + bv;
      p[Ndim] = acc[i][j][1] + bv;
      p[2 * Ndim] = acc[i][j][2] + bv;
      p[3 * Ndim] = acc[i][j][3] + bv;
    }
  }
}

extern "C" void kernel_launch(void* const* d_in, const int* in_sizes, int n_in,
                              void* d_out, int out_size, void* d_ws, size_t ws_size,
                              hipStream_t stream) {
  const float* x = (const float*)d_in[0];
  const float* w = (const float*)d_in[1];
  const float* bias = (const float*)d_in[2];
  float* out = (float*)d_out;

  uint8_t* ws = (uint8_t*)d_ws;
  uint8_t* qx = ws;                                  // M*K fp8
  uint8_t* qw = qx + (size_t)Mdim * Kdim;            // N*K fp8
  float* sx = (float*)(qw + (size_t)Ndim * Kdim);    // [KBLK][M]
  float* sw = sx + (size_t)KBLK * Mdim;              // [NBLK][KBLK]

  quant_x_kernel<<<(Mdim * Kdim / 16) / 256, 256, 0, stream>>>(x, qx, sx);
  quant_w_kernel<<<dim3(KBLK, NBLK), 256, 0, stream>>>(w, qw, sw);
  gemm_kernel<<<dim3(NBLK, Mdim / 128), 256, 0, stream>>>(qx, qw, sx, sw, bias, out);
}